// Round 1
// baseline (229.158 us; speedup 1.0000x reference)
//
#include <hip/hip_runtime.h>
#include <hip/hip_bf16.h>

// Problem constants: features (16384,128) fp32; B = 8192; D = 128.
// TEMP=1 -> t2=1; BETA=0.5; ALPHA=0.5; GAMMA=0.5.
// out = positive_loss + nl_a + nl_b + 0.5*(s_a + s_b), scalar fp32.

typedef __attribute__((ext_vector_type(8))) short short8;
typedef __attribute__((ext_vector_type(4))) float float4v;

#define NROWS 16384
#define BHALF 8192
#define D 128
#define NT 64            // 8192 / 128 tiles per dim
#define NPAIRS 2080      // NT*(NT+1)/2

__device__ __forceinline__ unsigned short f2bf(float x) {
    unsigned int u = __float_as_uint(x);
    u += 0x7fffu + ((u >> 16) & 1u);   // RNE
    return (unsigned short)(u >> 16);
}

// ---- Kernel 1: fp32 -> bf16 convert + row sum-of-squares ----
__global__ void prep_kernel(const float* __restrict__ f,
                            unsigned short* __restrict__ xbf,
                            float* __restrict__ xx) {
    int wave = threadIdx.x >> 6, lane = threadIdx.x & 63;
    int row = blockIdx.x * 4 + wave;
    const float2 v = *reinterpret_cast<const float2*>(f + (size_t)row * D + lane * 2);
    ushort2 st;
    st.x = f2bf(v.x);
    st.y = f2bf(v.y);
    *reinterpret_cast<ushort2*>(xbf + (size_t)row * D + lane * 2) = st;
    float s = v.x * v.x + v.y * v.y;
    #pragma unroll
    for (int off = 32; off; off >>= 1) s += __shfl_down(s, off, 64);
    if (lane == 0) xx[row] = s;
}

// ---- Kernel 2: positive loss (one wave per row) ----
__global__ void pos_kernel(const float* __restrict__ f, float* __restrict__ out) {
    int wave = threadIdx.x >> 6, lane = threadIdx.x & 63;
    int i = blockIdx.x * 4 + wave;
    const float2 va = *reinterpret_cast<const float2*>(f + (size_t)i * D + lane * 2);
    const float2 vb = *reinterpret_cast<const float2*>(f + (size_t)(BHALF + i) * D + lane * 2);
    float dx = va.x - vb.x, dy = va.y - vb.y;
    float s = dx * dx + dy * dy;
    #pragma unroll
    for (int off = 32; off; off >>= 1) s += __shfl_down(s, off, 64);
    if (lane == 0) {
        float ps = 1.0f / (s + 1.0f);
        float term = (ps - 10.0f) * (ps - 10.0f) - ps;  // -2*ALPHA*ps = -ps
        atomicAdd(out, term * (1.0f / (float)BHALF));
    }
}

// ---- Kernel 3: fused symmetric sim-reduction over 128x128 tiles ----
// grid = (NPAIRS, 2): blockIdx.y = matrix (0=a, 1=b); blockIdx.x = upper-tri pair.
__global__ __launch_bounds__(256, 2)
void neg_kernel(const unsigned short* __restrict__ xbf,
                const float* __restrict__ xx,
                float* __restrict__ out) {
    __shared__ unsigned short lT[2][128 * 128];  // 64 KiB, XOR-swizzled rows
    __shared__ float red[8];

    const int t = threadIdx.x;
    const int mat = blockIdx.y;
    const int moff = mat * BHALF;

    // decode upper-triangular pair index -> (bi, bj), bi <= bj
    int bi = 0;
    {
        int rem = blockIdx.x;
        while (rem >= NT - bi) { rem -= NT - bi; ++bi; }
        bi = bi;
        rem = rem;
        // bj computed below
        red[0] = red[0]; // no-op to keep structure simple
        // store rem in bi-adjacent var:
        // (we just recompute bj here)
        // bj = bi + rem;
        // fallthrough
        int bj_ = bi + rem;
        // stash in shared? no — keep in registers via local vars:
        // use goto-free structure:
        // (handled below by recomputing)
        // To keep it simple, recompute:
        (void)bj_;
    }
    // clean re-decode (uniform scalar work, <=64 iterations)
    int rem = blockIdx.x, bi2 = 0;
    while (rem >= NT - bi2) { rem -= NT - bi2; ++bi2; }
    const int tbi = bi2, tbj = bi2 + rem;

    const int gi0 = moff + tbi * 128;
    const int gj0 = moff + tbj * 128;

    // ---- stage both tiles to LDS (bf16, swizzled) ----
    #pragma unroll
    for (int half = 0; half < 2; ++half) {
        const int base = half ? gj0 : gi0;
        unsigned short* L = lT[half];
        #pragma unroll
        for (int c8 = 0; c8 < 8; ++c8) {
            int chunk = c8 * 256 + t;           // 0..2047
            int row = chunk >> 4, col16 = chunk & 15;
            uint4 v = *reinterpret_cast<const uint4*>(xbf + (size_t)(base + row) * D + col16 * 8);
            int boff = (col16 * 16) ^ ((row & 7) << 4);
            *reinterpret_cast<uint4*>(reinterpret_cast<char*>(L) + row * 256 + boff) = v;
        }
    }
    __syncthreads();

    const int lane = t & 63, wave = t >> 6;
    const int wr = wave >> 1, wc = wave & 1;
    const int l15 = lane & 15, g = lane >> 4;

    float4v acc[4][4] = {};

    #pragma unroll
    for (int kk = 0; kk < 4; ++kk) {
        short8 a[4], b[4];
        #pragma unroll
        for (int mi = 0; mi < 4; ++mi) {
            int row = wr * 64 + mi * 16 + l15;
            int boff = (kk * 64 + g * 16) ^ ((row & 7) << 4);
            a[mi] = *reinterpret_cast<short8*>(reinterpret_cast<char*>(lT[0]) + row * 256 + boff);
        }
        #pragma unroll
        for (int ni = 0; ni < 4; ++ni) {
            int row = wc * 64 + ni * 16 + l15;
            int boff = (kk * 64 + g * 16) ^ ((row & 7) << 4);
            b[ni] = *reinterpret_cast<short8*>(reinterpret_cast<char*>(lT[1]) + row * 256 + boff);
        }
        #pragma unroll
        for (int mi = 0; mi < 4; ++mi)
            #pragma unroll
            for (int ni = 0; ni < 4; ++ni)
                acc[mi][ni] = __builtin_amdgcn_mfma_f32_16x16x32_bf16(a[mi], b[ni], acc[mi][ni], 0, 0, 0);
    }

    // ---- fused epilogue ----
    const bool diag = (tbi == tbj);
    const int rbase = tbi * 128 + wr * 64;   // local (per-matrix) row base
    const int cbase = tbj * 128 + wc * 64;

    float xr[16], xc[4];
    #pragma unroll
    for (int mi = 0; mi < 4; ++mi)
        #pragma unroll
        for (int r = 0; r < 4; ++r)
            xr[mi * 4 + r] = xx[moff + rbase + mi * 16 + g * 4 + r];
    #pragma unroll
    for (int ni = 0; ni < 4; ++ni)
        xc[ni] = xx[moff + cbase + ni * 16 + l15];

    float aS = 0.0f, aN = 0.0f;
    #pragma unroll
    for (int mi = 0; mi < 4; ++mi) {
        #pragma unroll
        for (int ni = 0; ni < 4; ++ni) {
            #pragma unroll
            for (int r = 0; r < 4; ++r) {
                float dot = acc[mi][ni][r];
                float d = fmaxf(xr[mi * 4 + r] + xc[ni] - 2.0f * dot, 0.0f);
                float s = __builtin_amdgcn_rcpf(d + 1.0f);
                if (diag) {
                    int row = rbase + mi * 16 + g * 4 + r;
                    int col = cbase + ni * 16 + l15;
                    if (row == col) s = 0.0f;
                }
                aS += s;
                aN += __expf(0.5f * s) * s;
            }
        }
    }

    // ---- block reduction ----
    #pragma unroll
    for (int off = 32; off; off >>= 1) {
        aS += __shfl_down(aS, off, 64);
        aN += __shfl_down(aN, off, 64);
    }
    if (lane == 0) { red[wave * 2] = aS; red[wave * 2 + 1] = aN; }
    __syncthreads();
    if (t == 0) {
        float S = red[0] + red[2] + red[4] + red[6];
        float N = red[1] + red[3] + red[5] + red[7];
        float w = diag ? 1.0f : 2.0f;
        // neg_loss contribution: N/B ; regularization: GAMMA * S
        atomicAdd(out, w * (N * (1.0f / (float)BHALF) + 0.5f * S));
    }
}

extern "C" void kernel_launch(void* const* d_in, const int* in_sizes, int n_in,
                              void* d_out, int out_size, void* d_ws, size_t ws_size,
                              hipStream_t stream) {
    const float* f = (const float*)d_in[0];
    float* out = (float*)d_out;
    unsigned short* xbf = (unsigned short*)d_ws;
    float* xx = (float*)((char*)d_ws + (size_t)NROWS * D * sizeof(unsigned short));

    hipMemsetAsync(d_out, 0, out_size * sizeof(float), stream);
    prep_kernel<<<NROWS / 4, 256, 0, stream>>>(f, xbf, xx);
    pos_kernel<<<BHALF / 4, 256, 0, stream>>>(f, out);
    neg_kernel<<<dim3(NPAIRS, 2), 256, 0, stream>>>(xbf, xx, out);
}

// Round 4
// 117.703 us; speedup vs baseline: 1.9469x; 1.9469x over previous
//
#include <hip/hip_runtime.h>
#include <hip/hip_bf16.h>

// features (16384,128) fp32; B=8192; D=128. TEMP=1 -> t2=1; BETA=0.5; ALPHA=0.5; GAMMA=0.5.
// out = positive_loss + nl_a + nl_b + 0.5*(s_a + s_b), scalar fp32.
//
// Structure:
//  1) prep_pos_kernel: fp32->bf16 convert + row |x|^2 + positive loss partials (128 blocks)
//  2) neg_kernel: symmetric 128x128-tile GEMM-shaped fused sim-reduction (upper triangle only)
//  3) finish_kernel: sum 64 scratch accumulator slots -> d_out
// All block contributions go through 64 scratch slots to avoid same-address atomic chains
// (round-1 lesson: 8192 same-address atomics = 106us).

typedef __attribute__((ext_vector_type(8))) short short8;
typedef __attribute__((ext_vector_type(4))) float float4v;

#define NROWS 16384
#define BHALF 8192
#define D 128
#define NT 64            // 8192/128 tiles per dim
#define NPAIRS 2080      // NT*(NT+1)/2
#define NACC 64

__device__ __forceinline__ unsigned short f2bf(float x) {
    unsigned int u = __float_as_uint(x);
    u += 0x7fffu + ((u >> 16) & 1u);   // RNE
    return (unsigned short)(u >> 16);
}

// ---- Kernel 1: convert + row norms + positive loss ----
__global__ __launch_bounds__(256)
void prep_pos_kernel(const float* __restrict__ f,
                     unsigned short* __restrict__ xbf,
                     float* __restrict__ xx,
                     float* __restrict__ acc) {
    __shared__ float red[4];
    const int wave = threadIdx.x >> 6, lane = threadIdx.x & 63;
    const int gw = blockIdx.x * 4 + wave;   // 512 waves total
    float posAcc = 0.0f;

    #pragma unroll
    for (int p = 0; p < 16; ++p) {
        const int i = gw + p * 512;         // pair index 0..8191
        const float2 a = *reinterpret_cast<const float2*>(f + (size_t)i * D + lane * 2);
        const float2 b = *reinterpret_cast<const float2*>(f + (size_t)(i + BHALF) * D + lane * 2);
        ushort2 sa2, sb2;
        sa2.x = f2bf(a.x); sa2.y = f2bf(a.y);
        sb2.x = f2bf(b.x); sb2.y = f2bf(b.y);
        *reinterpret_cast<ushort2*>(xbf + (size_t)i * D + lane * 2) = sa2;
        *reinterpret_cast<ushort2*>(xbf + (size_t)(i + BHALF) * D + lane * 2) = sb2;
        float sa = a.x * a.x + a.y * a.y;
        float sb = b.x * b.x + b.y * b.y;
        float dx = a.x - b.x, dy = a.y - b.y;
        float sp = dx * dx + dy * dy;
        #pragma unroll
        for (int off = 32; off; off >>= 1) {
            sa += __shfl_down(sa, off, 64);
            sb += __shfl_down(sb, off, 64);
            sp += __shfl_down(sp, off, 64);
        }
        if (lane == 0) {
            xx[i] = sa;
            xx[i + BHALF] = sb;
            float ps = 1.0f / (sp + 1.0f);
            posAcc += (ps - 10.0f) * (ps - 10.0f) - ps;   // -2*ALPHA*ps = -ps
        }
    }
    if (lane == 0) red[wave] = posAcc;
    __syncthreads();
    if (threadIdx.x == 0) {
        float s = (red[0] + red[1] + red[2] + red[3]) * (1.0f / (float)BHALF);
        atomicAdd(&acc[blockIdx.x & (NACC - 1)], s);
    }
}

// ---- Kernel 2: fused symmetric sim-reduction over 128x128 tiles ----
// grid = (NPAIRS, 2): blockIdx.y = matrix (0=a,1=b); blockIdx.x = upper-tri pair.
// 512 threads = 8 waves (4 row-waves x 2 col-waves), each wave: 32x64 output.
__global__ __launch_bounds__(512, 4)
void neg_kernel(const unsigned short* __restrict__ xbf,
                const float* __restrict__ xx,
                float* __restrict__ acc) {
    __shared__ unsigned short lT[2][128 * 128];  // 64 KiB, XOR-swizzled 16B units
    __shared__ float red[16];

    const int t = threadIdx.x;
    const int mat = blockIdx.y;
    const int moff = mat * BHALF;

    // decode upper-triangular pair index -> (tbi, tbj), tbi <= tbj
    int rem = blockIdx.x, bi = 0;
    while (rem >= NT - bi) { rem -= NT - bi; ++bi; }
    const int tbi = bi, tbj = bi + rem;

    const int wave = t >> 6, lane = t & 63;

    // ---- stage both tiles via global_load_lds (width 16) ----
    // LDS dest is linear (wave-uniform base + lane*16); the XOR swizzle is applied to
    // the GLOBAL source address (involution), so swizzled reads below recover the data.
    #pragma unroll
    for (int half = 0; half < 2; ++half) {
        const int rowbase = moff + (half ? tbj : tbi) * 128;
        const char* gbase = (const char*)(xbf + (size_t)rowbase * D);
        #pragma unroll
        for (int p = 0; p < 4; ++p) {
            const int c = p * 512 + t;            // chunk 0..2047 (16B units)
            const int row = c >> 4, col16 = c & 15;
            const int gb = row * 256 + ((col16 * 16) ^ ((row & 7) << 4));
            const unsigned ldsoff = (unsigned)(p * 512 + wave * 64) * 16;  // wave-uniform
            __builtin_amdgcn_global_load_lds(
                (const __attribute__((address_space(1))) unsigned int*)(gbase + gb),
                (__attribute__((address_space(3))) unsigned int*)((char*)lT[half] + ldsoff),
                16, 0, 0);
        }
    }
    __syncthreads();

    const int wr = wave >> 1, wc = wave & 1;      // 4 x 2 wave grid
    const int l15 = lane & 15, g = lane >> 4;

    float4v accv[2][4] = {};

    #pragma unroll
    for (int kk = 0; kk < 4; ++kk) {
        short8 a[2], b[4];
        #pragma unroll
        for (int mi = 0; mi < 2; ++mi) {
            const int row = wr * 32 + mi * 16 + l15;
            const int boff = (kk * 64 + g * 16) ^ ((row & 7) << 4);
            a[mi] = *reinterpret_cast<short8*>(reinterpret_cast<char*>(lT[0]) + row * 256 + boff);
        }
        #pragma unroll
        for (int ni = 0; ni < 4; ++ni) {
            const int row = wc * 64 + ni * 16 + l15;
            const int boff = (kk * 64 + g * 16) ^ ((row & 7) << 4);
            b[ni] = *reinterpret_cast<short8*>(reinterpret_cast<char*>(lT[1]) + row * 256 + boff);
        }
        #pragma unroll
        for (int mi = 0; mi < 2; ++mi)
            #pragma unroll
            for (int ni = 0; ni < 4; ++ni)
                accv[mi][ni] = __builtin_amdgcn_mfma_f32_16x16x32_bf16(a[mi], b[ni], accv[mi][ni], 0, 0, 0);
    }

    // ---- fused epilogue ----
    const bool diag = (tbi == tbj);
    const int rbase = tbi * 128 + wr * 32;   // local (per-matrix) row base
    const int cbase = tbj * 128 + wc * 64;

    float xr[8], xc[4];
    #pragma unroll
    for (int mi = 0; mi < 2; ++mi)
        #pragma unroll
        for (int r = 0; r < 4; ++r)
            xr[mi * 4 + r] = xx[moff + rbase + mi * 16 + g * 4 + r];
    #pragma unroll
    for (int ni = 0; ni < 4; ++ni)
        xc[ni] = xx[moff + cbase + ni * 16 + l15];

    float aS = 0.0f, aN = 0.0f;
    #pragma unroll
    for (int mi = 0; mi < 2; ++mi) {
        #pragma unroll
        for (int ni = 0; ni < 4; ++ni) {
            #pragma unroll
            for (int r = 0; r < 4; ++r) {
                const float dot = accv[mi][ni][r];
                float d = fmaxf(xr[mi * 4 + r] + xc[ni] - 2.0f * dot, 0.0f);
                float s = __builtin_amdgcn_rcpf(d + 1.0f);
                if (diag) {
                    const int row = rbase + mi * 16 + g * 4 + r;
                    const int col = cbase + ni * 16 + l15;
                    if (row == col) s = 0.0f;
                }
                aS += s;
                aN += __expf(0.5f * s) * s;
            }
        }
    }

    // ---- block reduction ----
    #pragma unroll
    for (int off = 32; off; off >>= 1) {
        aS += __shfl_down(aS, off, 64);
        aN += __shfl_down(aN, off, 64);
    }
    if (lane == 0) { red[wave * 2] = aS; red[wave * 2 + 1] = aN; }
    __syncthreads();
    if (t == 0) {
        float S = 0.0f, N = 0.0f;
        #pragma unroll
        for (int w = 0; w < 8; ++w) { S += red[w * 2]; N += red[w * 2 + 1]; }
        const float w = diag ? 1.0f : 2.0f;
        // neg_loss contribution: N/B ; regularization: GAMMA * S
        atomicAdd(&acc[(blockIdx.x * 2 + blockIdx.y) & (NACC - 1)],
                  w * (N * (1.0f / (float)BHALF) + 0.5f * S));
    }
}

// ---- Kernel 3: final sum of scratch slots ----
__global__ void finish_kernel(const float* __restrict__ acc, float* __restrict__ out) {
    const int lane = threadIdx.x & 63;
    float v = acc[lane];
    #pragma unroll
    for (int off = 32; off; off >>= 1) v += __shfl_down(v, off, 64);
    if (lane == 0) out[0] = v;
}

extern "C" void kernel_launch(void* const* d_in, const int* in_sizes, int n_in,
                              void* d_out, int out_size, void* d_ws, size_t ws_size,
                              hipStream_t stream) {
    const float* f = (const float*)d_in[0];
    float* out = (float*)d_out;
    unsigned short* xbf = (unsigned short*)d_ws;
    float* xx = (float*)((char*)d_ws + (size_t)NROWS * D * sizeof(unsigned short));
    float* acc = xx + NROWS;

    hipMemsetAsync(acc, 0, NACC * sizeof(float), stream);
    prep_pos_kernel<<<128, 256, 0, stream>>>(f, xbf, xx, acc);
    neg_kernel<<<dim3(NPAIRS, 2), 512, 0, stream>>>(xbf, xx, acc);
    finish_kernel<<<1, 64, 0, stream>>>(acc, out);
}

// Round 8
// 104.939 us; speedup vs baseline: 2.1837x; 1.1216x over previous
//
#include <hip/hip_runtime.h>
#include <hip/hip_bf16.h>

// features (16384,128) fp32; B=8192; D=128. TEMP=1 -> t2=1; BETA=0.5; ALPHA=0.5; GAMMA=0.5.
// out = positive_loss + nl_a + nl_b + 0.5*(s_a + s_b), scalar fp32.
//
// Structure (3 kernels, no memset node):
//  1) prep_pos_kernel (256 blocks): fp32->bf16 + row |x|^2 + pos-loss partials (plain stores)
//     + block 0 zeroes negacc (harness poisons ws with 0xAA each launch).
//  2) neg_kernel (2080x2 blocks): symmetric 128x128-tile MFMA fused sim-reduction, upper
//     triangle only, weight 2 off-diagonal. exp() replaced by cubic Taylor (error <<
//     threshold: exp-term contributes ~64 of 2.66e5 output; threshold 5.3e3).
//  3) finish_kernel: sum 64 negacc slots + 256 prep partials -> d_out.
// Atomics only into 64 spread slots (round-1 lesson: same-address atomic chain = 13ns each).

typedef __attribute__((ext_vector_type(8))) short short8;
typedef __attribute__((ext_vector_type(4))) float float4v;

#define NROWS 16384
#define BHALF 8192
#define D 128
#define NT 64            // 8192/128 tiles per dim
#define NPAIRS 2080      // NT*(NT+1)/2
#define NACC 64
#define NPART 256

__device__ __forceinline__ unsigned short f2bf(float x) {
    unsigned int u = __float_as_uint(x);
    u += 0x7fffu + ((u >> 16) & 1u);   // RNE
    return (unsigned short)(u >> 16);
}

// ---- Kernel 1: convert + row norms + positive loss (2048 waves) ----
__global__ __launch_bounds__(512)
void prep_pos_kernel(const float* __restrict__ f,
                     unsigned short* __restrict__ xbf,
                     float* __restrict__ xx,
                     float* __restrict__ part,
                     float* __restrict__ negacc) {
    __shared__ float red[8];
    const int wave = threadIdx.x >> 6, lane = threadIdx.x & 63;
    const int gw = blockIdx.x * 8 + wave;   // 0..2047
    float posAcc = 0.0f;

    #pragma unroll
    for (int p = 0; p < 4; ++p) {
        const int i = gw + p * 2048;        // pair index 0..8191
        const float2 a = *reinterpret_cast<const float2*>(f + (size_t)i * D + lane * 2);
        const float2 b = *reinterpret_cast<const float2*>(f + (size_t)(i + BHALF) * D + lane * 2);
        ushort2 sa2, sb2;
        sa2.x = f2bf(a.x); sa2.y = f2bf(a.y);
        sb2.x = f2bf(b.x); sb2.y = f2bf(b.y);
        *reinterpret_cast<ushort2*>(xbf + (size_t)i * D + lane * 2) = sa2;
        *reinterpret_cast<ushort2*>(xbf + (size_t)(i + BHALF) * D + lane * 2) = sb2;
        float sa = a.x * a.x + a.y * a.y;
        float sb = b.x * b.x + b.y * b.y;
        float dx = a.x - b.x, dy = a.y - b.y;
        float sp = dx * dx + dy * dy;
        #pragma unroll
        for (int off = 32; off; off >>= 1) {
            sa += __shfl_down(sa, off, 64);
            sb += __shfl_down(sb, off, 64);
            sp += __shfl_down(sp, off, 64);
        }
        if (lane == 0) {
            xx[i] = sa;
            xx[i + BHALF] = sb;
            float ps = 1.0f / (sp + 1.0f);
            posAcc += (ps - 10.0f) * (ps - 10.0f) - ps;   // -2*ALPHA*ps = -ps
        }
    }
    if (lane == 0) red[wave] = posAcc;
    if (blockIdx.x == 0 && threadIdx.x < NACC) negacc[threadIdx.x] = 0.0f;
    __syncthreads();
    if (threadIdx.x == 0) {
        float s = 0.0f;
        #pragma unroll
        for (int w = 0; w < 8; ++w) s += red[w];
        part[blockIdx.x] = s;                 // raw sum; /B applied in finish
    }
}

// ---- Kernel 2: fused symmetric sim-reduction over 128x128 tiles ----
// grid = (NPAIRS, 2): blockIdx.y = matrix (0=a,1=b); blockIdx.x = upper-tri pair.
// 512 threads = 8 waves (4 row-waves x 2 col-waves), each wave: 32x64 output.
__global__ __launch_bounds__(512, 4)
void neg_kernel(const unsigned short* __restrict__ xbf,
                const float* __restrict__ xx,
                float* __restrict__ negacc) {
    __shared__ unsigned short lT[2][128 * 128];  // 64 KiB, XOR-swizzled 16B units
    __shared__ float red[16];

    const int t = threadIdx.x;
    const int mat = blockIdx.y;
    const int moff = mat * BHALF;

    // decode upper-triangular pair index -> (tbi, tbj), tbi <= tbj
    int rem = blockIdx.x, bi = 0;
    while (rem >= NT - bi) { rem -= NT - bi; ++bi; }
    const int tbi = bi, tbj = bi + rem;

    const int wave = t >> 6, lane = t & 63;

    // ---- stage both tiles via global_load_lds (width 16) ----
    // LDS dest linear (wave-uniform base + lane*16); XOR swizzle applied to the GLOBAL
    // source address (involution), so swizzled reads below recover the data (rule #21).
    #pragma unroll
    for (int half = 0; half < 2; ++half) {
        const int rowbase = moff + (half ? tbj : tbi) * 128;
        const char* gbase = (const char*)(xbf + (size_t)rowbase * D);
        #pragma unroll
        for (int p = 0; p < 4; ++p) {
            const int c = p * 512 + t;            // chunk 0..2047 (16B units)
            const int row = c >> 4, col16 = c & 15;
            const int gb = row * 256 + ((col16 * 16) ^ ((row & 7) << 4));
            const unsigned ldsoff = (unsigned)(p * 512 + wave * 64) * 16;  // wave-uniform
            __builtin_amdgcn_global_load_lds(
                (const __attribute__((address_space(1))) unsigned int*)(gbase + gb),
                (__attribute__((address_space(3))) unsigned int*)((char*)lT[half] + ldsoff),
                16, 0, 0);
        }
    }
    __syncthreads();

    const int wr = wave >> 1, wc = wave & 1;      // 4 x 2 wave grid
    const int l15 = lane & 15, g = lane >> 4;

    float4v accv[2][4] = {};

    #pragma unroll
    for (int kk = 0; kk < 4; ++kk) {
        short8 a[2], b[4];
        #pragma unroll
        for (int mi = 0; mi < 2; ++mi) {
            const int row = wr * 32 + mi * 16 + l15;
            const int boff = (kk * 64 + g * 16) ^ ((row & 7) << 4);
            a[mi] = *reinterpret_cast<short8*>(reinterpret_cast<char*>(lT[0]) + row * 256 + boff);
        }
        #pragma unroll
        for (int ni = 0; ni < 4; ++ni) {
            const int row = wc * 64 + ni * 16 + l15;
            const int boff = (kk * 64 + g * 16) ^ ((row & 7) << 4);
            b[ni] = *reinterpret_cast<short8*>(reinterpret_cast<char*>(lT[1]) + row * 256 + boff);
        }
        #pragma unroll
        for (int mi = 0; mi < 2; ++mi)
            #pragma unroll
            for (int ni = 0; ni < 4; ++ni)
                accv[mi][ni] = __builtin_amdgcn_mfma_f32_16x16x32_bf16(a[mi], b[ni], accv[mi][ni], 0, 0, 0);
    }

    // ---- fused epilogue (no transcendental exp: cubic Taylor of exp(s/2), s in [0,1]) ----
    const bool diag = (tbi == tbj);
    const int rbase = tbi * 128 + wr * 32;   // local (per-matrix) row base
    const int cbase = tbj * 128 + wc * 64;

    float xr1[8], xc[4];
    #pragma unroll
    for (int mi = 0; mi < 2; ++mi)
        #pragma unroll
        for (int r = 0; r < 4; ++r)
            xr1[mi * 4 + r] = xx[moff + rbase + mi * 16 + g * 4 + r] + 1.0f;  // fold +1 of d+1
    #pragma unroll
    for (int ni = 0; ni < 4; ++ni)
        xc[ni] = xx[moff + cbase + ni * 16 + l15];

    float aS0 = 0.0f, aS1 = 0.0f, aN0 = 0.0f, aN1 = 0.0f;
    #pragma unroll
    for (int mi = 0; mi < 2; ++mi) {
        #pragma unroll
        for (int ni = 0; ni < 4; ++ni) {
            #pragma unroll
            for (int r = 0; r < 4; ++r) {
                const float dot = accv[mi][ni][r];
                // d+1 = xr+xc-2dot+1 ; max(d,0)+1 = max(d+1, 1)
                float t1 = xr1[mi * 4 + r] + xc[ni];
                float m = fmaxf(fmaf(dot, -2.0f, t1), 1.0f);
                float s = __builtin_amdgcn_rcpf(m);
                if (diag) {
                    const int row = rbase + mi * 16 + g * 4 + r;
                    const int col = cbase + ni * 16 + l15;
                    if (row == col) s = 0.0f;
                }
                // exp(0.5s) ~= 1 + s/2 + s^2/8 + s^3/48  (|err| <= 0.0026 s^4)
                float p = fmaf(s, 0.02083333333f, 0.125f);
                p = fmaf(s, p, 0.5f);
                p = fmaf(s, p, 1.0f);
                if (r & 1) { aS1 += s; aN1 = fmaf(p, s, aN1); }
                else       { aS0 += s; aN0 = fmaf(p, s, aN0); }
            }
        }
    }
    float aS = aS0 + aS1, aN = aN0 + aN1;

    // ---- block reduction ----
    #pragma unroll
    for (int off = 32; off; off >>= 1) {
        aS += __shfl_down(aS, off, 64);
        aN += __shfl_down(aN, off, 64);
    }
    if (lane == 0) { red[wave * 2] = aS; red[wave * 2 + 1] = aN; }
    __syncthreads();
    if (t == 0) {
        float S = 0.0f, N = 0.0f;
        #pragma unroll
        for (int w = 0; w < 8; ++w) { S += red[w * 2]; N += red[w * 2 + 1]; }
        const float w = diag ? 1.0f : 2.0f;
        // neg_loss contribution: N/B ; regularization: GAMMA * S
        atomicAdd(&negacc[(blockIdx.x * 2 + blockIdx.y) & (NACC - 1)],
                  w * (N * (1.0f / (float)BHALF) + 0.5f * S));
    }
}

// ---- Kernel 3: final sum (64 neg slots + 256 prep partials) ----
__global__ void finish_kernel(const float* __restrict__ negacc,
                              const float* __restrict__ part,
                              float* __restrict__ out) {
    const int lane = threadIdx.x & 63;
    float v = negacc[lane];
    float pp = part[lane] + part[lane + 64] + part[lane + 128] + part[lane + 192];
    v = fmaf(pp, 1.0f / (float)BHALF, v);
    #pragma unroll
    for (int off = 32; off; off >>= 1) v += __shfl_down(v, off, 64);
    if (lane == 0) out[0] = v;
}

extern "C" void kernel_launch(void* const* d_in, const int* in_sizes, int n_in,
                              void* d_out, int out_size, void* d_ws, size_t ws_size,
                              hipStream_t stream) {
    const float* f = (const float*)d_in[0];
    float* out = (float*)d_out;
    unsigned short* xbf = (unsigned short*)d_ws;
    float* xx = (float*)((char*)d_ws + (size_t)NROWS * D * sizeof(unsigned short));
    float* negacc = xx + NROWS;
    float* part = negacc + NACC;

    prep_pos_kernel<<<NPART, 512, 0, stream>>>(f, xbf, xx, part, negacc);
    neg_kernel<<<dim3(NPAIRS, 2), 512, 0, stream>>>(xbf, xx, negacc);
    finish_kernel<<<1, 64, 0, stream>>>(negacc, part, out);
}